// Round 9
// baseline (169.037 us; speedup 1.0000x reference)
//
#include <hip/hip_runtime.h>
#include <math.h>

// Problem constants (from reference)
constexpr int B_ = 16, T_ = 256, D_ = 384, M_ = 2048, F_ = 256, NMEL_ = 80;
constexpr float PACE_ = 1.0f, MAXDUR_ = 75.0f;
constexpr int R_ = B_ * T_;  // 4096 total rows

typedef __attribute__((ext_vector_type(8))) short bf16x8;
typedef __attribute__((ext_vector_type(4))) float f32x4_;

static __device__ __forceinline__ unsigned short f2bf(float x) {
    union { float f; unsigned int u; } v; v.f = x;
    const unsigned int r = v.u + 0x7fffu + ((v.u >> 16) & 1u);  // RNE
    return (unsigned short)(r >> 16);
}

// ---------------------------------------------------------------------------
// Repack conv weight w[F_,CIN,3] fp32 -> bf16 16x16x32 B-fragment order:
//   p[ ((k*(F_/16) + fn)*(CIN/32) + c)*512 + lane*8 + j ]
//     = w[f = fn*16+(lane&15)][d = c*32+(lane>>4)*8+j][k]
// ---------------------------------------------------------------------------
template <int CIN>
static __device__ __forceinline__ void repack_dev(
    int gid, const float* __restrict__ w, unsigned short* __restrict__ p)
{
    constexpr int NC = CIN / 32;
    const int lane = gid & 63;
    int rest = gid >> 6;
    const int c = rest % NC;  rest /= NC;
    const int fn = rest % (F_ / 16);
    const int k  = rest / (F_ / 16);
    const int f = fn * 16 + (lane & 15);
    const int d = c * 32 + (lane >> 4) * 8;
    uint4 o;
    unsigned short* op = (unsigned short*)&o;
#pragma unroll
    for (int j = 0; j < 8; j++)
        op[j] = f2bf(w[((size_t)f * CIN + d + j) * 3 + k]);
    ((uint4*)p)[gid] = o;
}

// ---------------------------------------------------------------------------
// PREP kernel (blockIdx-partitioned, all sections independent):
//   [0,2)      pitch rank-3 precompute: Pc[k][n] (k<3: we[:,k]@proj[n],
//              k=3: be@proj[n]) — replaces the old 768-block pitch_add
//   [2,17)     repack proj_w -> pwb
//   [17,305)   repack conv0 weights (dur, pitch)
//   [305,497)  repack conv1 weights (dur, pitch)
// regulate moved into the mel blocks of mega (removes serial dependency).
// ---------------------------------------------------------------------------
constexpr int PP_BLK = 2;
constexpr int PJ_BLK = 15;                      // 3840/256
constexpr int R0_BLK = 3 * F_ * D_ / 8 / 256;   // 144
constexpr int R1_BLK = 3 * F_ * F_ / 8 / 256;   // 96
constexpr int PREP_BLOCKS = PP_BLK + PJ_BLK + 2 * R0_BLK + 2 * R1_BLK;  // 497

__global__ __launch_bounds__(256) void prep_kernel(
    const float* __restrict__ we, const float* __restrict__ be,
    const float* __restrict__ projw, unsigned short* __restrict__ pwb,
    float* __restrict__ Pc,
    const float* __restrict__ c0wd, const float* __restrict__ c0wp,
    unsigned short* __restrict__ p0d, unsigned short* __restrict__ p0p,
    const float* __restrict__ c1wd, const float* __restrict__ c1wp,
    unsigned short* __restrict__ p1d, unsigned short* __restrict__ p1p)
{
    const int bx = blockIdx.x, tid = threadIdx.x;
    if (bx < PP_BLK) {
        // Pc[k*80+n]: k<3 -> sum_d proj[n,d]*we[d*3+k]; k=3 -> sum_d proj[n,d]*be[d]
        const int gid = bx * 256 + tid;   // over 320
        if (gid < 320) {
            const int n = gid % 80;
            const int k = gid / 80;
            const float* pr = projw + (size_t)n * D_;
            float s = 0.f;
            if (k < 3) {
#pragma unroll 4
                for (int d = 0; d < D_; d++) s = fmaf(pr[d], we[d * 3 + k], s);
            } else {
#pragma unroll 4
                for (int d = 0; d < D_; d++) s = fmaf(pr[d], be[d], s);
            }
            Pc[k * 80 + n] = s;
        }
    } else if (bx < PP_BLK + PJ_BLK) {
        const int gid = (bx - PP_BLK) * 256 + tid;  // over 3840
        const int lane = gid & 63;
        const int rest = gid >> 6;
        const int nt = rest % 5;
        const int c  = rest / 5;
        const int n = nt * 16 + (lane & 15);
        const int k = c * 32 + (lane >> 4) * 8;
        uint4 o;
        unsigned short* op = (unsigned short*)&o;
#pragma unroll
        for (int j = 0; j < 8; j++)
            op[j] = f2bf(projw[(size_t)n * D_ + k + j]);
        ((uint4*)pwb)[gid] = o;
    } else if (bx < PP_BLK + PJ_BLK + 2 * R0_BLK) {
        const int i = bx - (PP_BLK + PJ_BLK);
        const int sel = (i >= R0_BLK) ? 1 : 0;
        const int gid = (i - sel * R0_BLK) * 256 + tid;
        repack_dev<D_>(gid, sel ? c0wp : c0wd, sel ? p0p : p0d);
    } else {
        const int i = bx - (PP_BLK + PJ_BLK + 2 * R0_BLK);
        const int sel = (i >= R1_BLK) ? 1 : 0;
        const int gid = (i - sel * R1_BLK) * 256 + tid;
        repack_dev<F_>(gid, sel ? c1wp : c1wd, sel ? p1p : p1d);
    }
}

// ---------------------------------------------------------------------------
// Fully fused predictor, 32 output rows / 512 threads (8 waves) per block
// (R8 structure, unchanged): conv0+ReLU+LN0 over 48 h-rows -> h in LDS ->
// conv1+ReLU+LN1+FC. Wave w owns channels w*32..w*32+31. B ping-pong +
// sched_barrier(0). __launch_bounds__(512,4): 128-VGPR cap, 2 blocks/CU.
// ---------------------------------------------------------------------------
constexpr int LDX_ = D_ + 8;   // 392, input stage stride (bf16)
constexpr int LDH_ = F_ + 8;   // 264, h stride (bf16)
constexpr int XS_BYTES = 50 * LDX_ * 2;                 // 39200 (> 48*LDH_*2)
constexpr int SMEM_A = XS_BYTES + 2 * 8 * 48 * 4;       // + reds/redq = 42272

#define MFMA16(a, b, c) __builtin_amdgcn_mfma_f32_16x16x32_bf16(a, b, c, 0, 0, 0)

static __device__ __forceinline__ void predictor_body(
    const int bx, char* smem,
    const float* __restrict__ x, const float* __restrict__ imask,
    const unsigned short* __restrict__ pw0, const float* __restrict__ b0,
    const float* __restrict__ g0, const float* __restrict__ be0,
    const unsigned short* __restrict__ pw1, const float* __restrict__ b1,
    const float* __restrict__ g1, const float* __restrict__ be1,
    const float* __restrict__ fw, const float* __restrict__ fbp,
    float* __restrict__ pred, float* __restrict__ durpred)
{
    unsigned short* xs = (unsigned short*)smem;           // [50][LDX_]
    unsigned short* hs = (unsigned short*)smem;           // [48][LDH_] (reuse)
    float* reds = (float*)(smem + XS_BYTES);              // [8][48]
    float* redq = reds + 8 * 48;

    const int r0  = bx * 32;          // 32-row tiles never cross a batch
    const int bb  = r0 >> 8;
    const int tl  = r0 & 255;
    const int tid = threadIdx.x;

    // ---- stage input rows tl-9 .. tl+40 (50 rows), masked, fp32->bf16
#pragma unroll
    for (int k = 0; k < 5; k++) {
        const int i = k * 512 + tid;
        if (k == 4 && tid >= 352) break;
        const int row = i / (D_ / 8);
        const int dd  = (i - row * (D_ / 8)) * 8;
        const int t   = tl - 9 + row;
        ushort4 o0 = {0, 0, 0, 0}, o1 = {0, 0, 0, 0};
        if (t >= 0 && t < 256) {
            const float m = imask[bb * 256 + t];
            const float* xr = x + (size_t)(bb * 256 + t) * D_ + dd;
            const float4 v0 = *(const float4*)xr;
            const float4 v1 = *(const float4*)(xr + 4);
            o0.x = f2bf(v0.x * m); o0.y = f2bf(v0.y * m);
            o0.z = f2bf(v0.z * m); o0.w = f2bf(v0.w * m);
            o1.x = f2bf(v1.x * m); o1.y = f2bf(v1.y * m);
            o1.z = f2bf(v1.z * m); o1.w = f2bf(v1.w * m);
        }
        *(ushort4*)(&xs[row * LDX_ + dd])     = o0;
        *(ushort4*)(&xs[row * LDX_ + dd + 4]) = o1;
    }
    __syncthreads();

    const int w = tid >> 6, l = tid & 63;     // w in [0,8)
    const int q = l >> 4, lm = l & 15;
    const unsigned short* pwl0 = pw0 + l * 8;
    const unsigned short* pwl1 = pw1 + l * 8;

    // ===== conv0 over 48 h-rows (3 m-tiles), 2 nf/wave, ping-pong B =====
    f32x4_ acc0[3][2];
#pragma unroll
    for (int mt = 0; mt < 3; mt++)
#pragma unroll
        for (int i = 0; i < 2; i++)
#pragma unroll
            for (int k = 0; k < 4; k++) acc0[mt][i][k] = 0.f;

    {
        bf16x8 bA[2][3], bB[2][3];
#pragma unroll
        for (int i = 0; i < 2; i++)
#pragma unroll
            for (int tap = 0; tap < 3; tap++)
                bA[i][tap] = *(const bf16x8*)(
                    pwl0 + ((((size_t)tap * 16 + (w * 2 + i)) * 12 + 0) << 9));

        for (int cc = 0; cc < 12; cc += 2) {
            {   // even: prefetch cc+1 -> bB, compute cc with bA
#pragma unroll
                for (int i = 0; i < 2; i++)
#pragma unroll
                    for (int tap = 0; tap < 3; tap++)
                        bB[i][tap] = *(const bf16x8*)(
                            pwl0 + ((((size_t)tap * 16 + (w * 2 + i)) * 12 + cc + 1) << 9));
                __builtin_amdgcn_sched_barrier(0);
#pragma unroll
                for (int mt = 0; mt < 3; mt++) {
                    bf16x8 a[3];
#pragma unroll
                    for (int tap = 0; tap < 3; tap++)
                        a[tap] = *(const bf16x8*)(
                            &xs[(mt * 16 + lm + tap) * LDX_ + cc * 32 + q * 8]);
#pragma unroll
                    for (int i = 0; i < 2; i++)
#pragma unroll
                        for (int tap = 0; tap < 3; tap++)
                            acc0[mt][i] = MFMA16(a[tap], bA[i][tap], acc0[mt][i]);
                }
            }
            {   // odd: prefetch cc+2 -> bA, compute cc+1 with bB
                if (cc + 2 < 12) {
#pragma unroll
                    for (int i = 0; i < 2; i++)
#pragma unroll
                        for (int tap = 0; tap < 3; tap++)
                            bA[i][tap] = *(const bf16x8*)(
                                pwl0 + ((((size_t)tap * 16 + (w * 2 + i)) * 12 + cc + 2) << 9));
                }
                __builtin_amdgcn_sched_barrier(0);
#pragma unroll
                for (int mt = 0; mt < 3; mt++) {
                    bf16x8 a[3];
#pragma unroll
                    for (int tap = 0; tap < 3; tap++)
                        a[tap] = *(const bf16x8*)(
                            &xs[(mt * 16 + lm + tap) * LDX_ + (cc + 1) * 32 + q * 8]);
#pragma unroll
                    for (int i = 0; i < 2; i++)
#pragma unroll
                        for (int tap = 0; tap < 3; tap++)
                            acc0[mt][i] = MFMA16(a[tap], bB[i][tap], acc0[mt][i]);
                }
            }
        }
    }

    // bias+ReLU. C/D layout: col=lane&15 (f), row=(lane>>4)*4+reg
    float v0[3][2][4];
#pragma unroll
    for (int i = 0; i < 2; i++) {
        const float bs = b0[w * 32 + i * 16 + lm];
#pragma unroll
        for (int mt = 0; mt < 3; mt++)
#pragma unroll
            for (int r = 0; r < 4; r++)
                v0[mt][i][r] = fmaxf(acc0[mt][i][r] + bs, 0.f);
    }

    // LN0 partials: per-lane over 2 nf, shfl over 16 lm-lanes, LDS over 8 waves
    {
        float s[3][4], t2[3][4];
#pragma unroll
        for (int mt = 0; mt < 3; mt++)
#pragma unroll
            for (int r = 0; r < 4; r++) {
                s[mt][r]  = v0[mt][0][r] + v0[mt][1][r];
                t2[mt][r] = v0[mt][0][r] * v0[mt][0][r] + v0[mt][1][r] * v0[mt][1][r];
            }
#pragma unroll
        for (int off = 1; off <= 8; off <<= 1)
#pragma unroll
            for (int mt = 0; mt < 3; mt++)
#pragma unroll
                for (int r = 0; r < 4; r++) {
                    s[mt][r]  += __shfl_xor(s[mt][r], off);
                    t2[mt][r] += __shfl_xor(t2[mt][r], off);
                }
        if (lm == 0) {
#pragma unroll
            for (int mt = 0; mt < 3; mt++)
#pragma unroll
                for (int r = 0; r < 4; r++) {
                    reds[w * 48 + mt * 16 + q * 4 + r] = s[mt][r];
                    redq[w * 48 + mt * 16 + q * 4 + r] = t2[mt][r];
                }
        }
    }
    __syncthreads();   // also: all xs reads complete -> hs overwrite safe

    // normalize + write h into LDS (zero rows whose t is outside the batch)
    {
        float mu[3][4], rs[3][4];
#pragma unroll
        for (int mt = 0; mt < 3; mt++)
#pragma unroll
            for (int r = 0; r < 4; r++) {
                const int hr = mt * 16 + q * 4 + r;
                float ts = 0.f, tq = 0.f;
#pragma unroll
                for (int ww = 0; ww < 8; ww++) {
                    ts += reds[ww * 48 + hr];
                    tq += redq[ww * 48 + hr];
                }
                const float m_ = ts * (1.f / F_);
                mu[mt][r] = m_;
                rs[mt][r] = rsqrtf(tq * (1.f / F_) - m_ * m_ + 1e-5f);
            }
#pragma unroll
        for (int i = 0; i < 2; i++) {
            const int f = w * 32 + i * 16 + lm;
            const float gg = g0[f], bb2 = be0[f];
#pragma unroll
            for (int mt = 0; mt < 3; mt++)
#pragma unroll
                for (int r = 0; r < 4; r++) {
                    const int hr = mt * 16 + q * 4 + r;
                    const int t  = tl - 8 + hr;
                    const float o = (t >= 0 && t < 256)
                        ? (v0[mt][i][r] - mu[mt][r]) * rs[mt][r] * gg + bb2 : 0.f;
                    hs[hr * LDH_ + f] = f2bf(o);
                }
        }
    }
    __syncthreads();

    // ===== conv1 over 32 rows (2 m-tiles), 2 nf/wave, ping-pong B =====
    f32x4_ acc1[2][2];
#pragma unroll
    for (int mt = 0; mt < 2; mt++)
#pragma unroll
        for (int i = 0; i < 2; i++)
#pragma unroll
            for (int k = 0; k < 4; k++) acc1[mt][i][k] = 0.f;

    {
        bf16x8 bA[2][3], bB[2][3];
#pragma unroll
        for (int i = 0; i < 2; i++)
#pragma unroll
            for (int tap = 0; tap < 3; tap++)
                bA[i][tap] = *(const bf16x8*)(
                    pwl1 + ((((size_t)tap * 16 + (w * 2 + i)) * 8 + 0) << 9));

        for (int cc = 0; cc < 8; cc += 2) {
            {   // even
#pragma unroll
                for (int i = 0; i < 2; i++)
#pragma unroll
                    for (int tap = 0; tap < 3; tap++)
                        bB[i][tap] = *(const bf16x8*)(
                            pwl1 + ((((size_t)tap * 16 + (w * 2 + i)) * 8 + cc + 1) << 9));
                __builtin_amdgcn_sched_barrier(0);
#pragma unroll
                for (int mt = 0; mt < 2; mt++) {
                    bf16x8 a[3];
#pragma unroll
                    for (int tap = 0; tap < 3; tap++)
                        a[tap] = *(const bf16x8*)(
                            &hs[(mt * 16 + lm + 7 + tap) * LDH_ + cc * 32 + q * 8]);
#pragma unroll
                    for (int i = 0; i < 2; i++)
#pragma unroll
                        for (int tap = 0; tap < 3; tap++)
                            acc1[mt][i] = MFMA16(a[tap], bA[i][tap], acc1[mt][i]);
                }
            }
            {   // odd
                if (cc + 2 < 8) {
#pragma unroll
                    for (int i = 0; i < 2; i++)
#pragma unroll
                        for (int tap = 0; tap < 3; tap++)
                            bA[i][tap] = *(const bf16x8*)(
                                pwl1 + ((((size_t)tap * 16 + (w * 2 + i)) * 8 + cc + 2) << 9));
                }
                __builtin_amdgcn_sched_barrier(0);
#pragma unroll
                for (int mt = 0; mt < 2; mt++) {
                    bf16x8 a[3];
#pragma unroll
                    for (int tap = 0; tap < 3; tap++)
                        a[tap] = *(const bf16x8*)(
                            &hs[(mt * 16 + lm + 7 + tap) * LDH_ + (cc + 1) * 32 + q * 8]);
#pragma unroll
                    for (int i = 0; i < 2; i++)
#pragma unroll
                        for (int tap = 0; tap < 3; tap++)
                            acc1[mt][i] = MFMA16(a[tap], bB[i][tap], acc1[mt][i]);
                }
            }
        }
    }

    float v1[2][2][4];
#pragma unroll
    for (int i = 0; i < 2; i++) {
        const float bs = b1[w * 32 + i * 16 + lm];
#pragma unroll
        for (int mt = 0; mt < 2; mt++)
#pragma unroll
            for (int r = 0; r < 4; r++)
                v1[mt][i][r] = fmaxf(acc1[mt][i][r] + bs, 0.f);
    }

    // LN1 partials
    {
        float s[2][4], t2[2][4];
#pragma unroll
        for (int mt = 0; mt < 2; mt++)
#pragma unroll
            for (int r = 0; r < 4; r++) {
                s[mt][r]  = v1[mt][0][r] + v1[mt][1][r];
                t2[mt][r] = v1[mt][0][r] * v1[mt][0][r] + v1[mt][1][r] * v1[mt][1][r];
            }
#pragma unroll
        for (int off = 1; off <= 8; off <<= 1)
#pragma unroll
            for (int mt = 0; mt < 2; mt++)
#pragma unroll
                for (int r = 0; r < 4; r++) {
                    s[mt][r]  += __shfl_xor(s[mt][r], off);
                    t2[mt][r] += __shfl_xor(t2[mt][r], off);
                }
        __syncthreads();   // conv1's hs reads + LN0 reds reads done
        if (lm == 0) {
#pragma unroll
            for (int mt = 0; mt < 2; mt++)
#pragma unroll
                for (int r = 0; r < 4; r++) {
                    reds[w * 32 + mt * 16 + q * 4 + r] = s[mt][r];
                    redq[w * 32 + mt * 16 + q * 4 + r] = t2[mt][r];
                }
        }
    }
    __syncthreads();

    float mu1[2][4], rs1[2][4];
#pragma unroll
    for (int mt = 0; mt < 2; mt++)
#pragma unroll
        for (int r = 0; r < 4; r++) {
            const int or_ = mt * 16 + q * 4 + r;
            float ts = 0.f, tq = 0.f;
#pragma unroll
            for (int ww = 0; ww < 8; ww++) {
                ts += reds[ww * 32 + or_];
                tq += redq[ww * 32 + or_];
            }
            const float m_ = ts * (1.f / F_);
            mu1[mt][r] = m_;
            rs1[mt][r] = rsqrtf(tq * (1.f / F_) - m_ * m_ + 1e-5f);
        }

    // FC head: pred[row] = (dot(LN1(v1), fw) + fb) * mask[row]
    float fcp[2][4];
#pragma unroll
    for (int mt = 0; mt < 2; mt++)
#pragma unroll
        for (int r = 0; r < 4; r++) fcp[mt][r] = 0.f;
#pragma unroll
    for (int i = 0; i < 2; i++) {
        const int f = w * 32 + i * 16 + lm;
        const float gg = g1[f], bb2 = be1[f], wv = fw[f];
#pragma unroll
        for (int mt = 0; mt < 2; mt++)
#pragma unroll
            for (int r = 0; r < 4; r++)
                fcp[mt][r] += ((v1[mt][i][r] - mu1[mt][r]) * rs1[mt][r] * gg + bb2) * wv;
    }
#pragma unroll
    for (int off = 1; off <= 8; off <<= 1)
#pragma unroll
        for (int mt = 0; mt < 2; mt++)
#pragma unroll
            for (int r = 0; r < 4; r++) fcp[mt][r] += __shfl_xor(fcp[mt][r], off);
    __syncthreads();   // mu1/rs1 reads of reds complete
    if (lm == 0) {
#pragma unroll
        for (int mt = 0; mt < 2; mt++)
#pragma unroll
            for (int r = 0; r < 4; r++)
                reds[w * 32 + mt * 16 + q * 4 + r] = fcp[mt][r];
    }
    __syncthreads();
    if (tid < 32) {
        float tot = fbp[0];
#pragma unroll
        for (int ww = 0; ww < 8; ww++) tot += reds[ww * 32 + tid];
        const int row = r0 + tid;
        const float p = tot * imask[row];
        pred[row] = p;
        if (durpred) durpred[row] = fminf(fmaxf(expf(p) - 1.f, 0.f), MAXDUR_);
    }
}

// ---------------------------------------------------------------------------
// Launch 2: predictors (dur blocks 0..127, pitch 128..255) ∥ mel gather-GEMM
// (blocks 256..511), 512 threads each. Mel now: self-contained regulate
// (LDS scan + searchsorted), A gathered from RAW enc_out (f32->bf16 on load),
// pitch conditioning applied as rank-3 epilogue term via Pc.
// ---------------------------------------------------------------------------
__global__ __launch_bounds__(512, 4) void mega_kernel(
    const float* __restrict__ enc_out, const float* __restrict__ enc_mask,
    const unsigned short* __restrict__ p0d, const unsigned short* __restrict__ p0p,
    const float* __restrict__ c0b_d, const float* __restrict__ c0b_p,
    const float* __restrict__ g0_d, const float* __restrict__ be0_d,
    const float* __restrict__ g0_p, const float* __restrict__ be0_p,
    const unsigned short* __restrict__ p1d, const unsigned short* __restrict__ p1p,
    const float* __restrict__ c1b_d, const float* __restrict__ c1b_p,
    const float* __restrict__ g1_d, const float* __restrict__ be1_d,
    const float* __restrict__ g1_p, const float* __restrict__ be1_p,
    const float* __restrict__ fw_d, const float* __restrict__ fw_p,
    const float* __restrict__ fb_d, const float* __restrict__ fb_p,
    float* __restrict__ log_dur, float* __restrict__ pitch_prd,
    float* __restrict__ durpred,
    const int* __restrict__ dur, const float* __restrict__ pt,
    const float* __restrict__ Pc,
    const unsigned short* __restrict__ pwb,
    const float* __restrict__ pb,
    float* __restrict__ dec_mask, float* __restrict__ mel)
{
    __shared__ __align__(16) char smem[SMEM_A];
    const int bxx = blockIdx.x;
    if (bxx < 256) {
        const int z = bxx >> 7;
        predictor_body(bxx & 127, smem,
            enc_out, enc_mask,
            z ? p0p : p0d, z ? c0b_p : c0b_d,
            z ? g0_p : g0_d, z ? be0_p : be0_d,
            z ? p1p : p1d, z ? c1b_p : c1b_d,
            z ? g1_p : g1_d, z ? be1_p : be1_d,
            z ? fw_p : fw_d, z ? fb_p : fb_d,
            z ? pitch_prd : log_dur, z ? nullptr : durpred);
        return;
    }
    // ---- mel branch: 128 j-rows per block, self-contained regulate.
    int* cums = (int*)smem;          // [256]
    int* ids  = cums + 256;          // [128]
    const int i  = bxx - 256;
    const int b  = i >> 4;
    const int j0 = (i & 15) * 128;
    const int tid = threadIdx.x;

    if (tid < 256) cums[tid] = (int)rintf((float)dur[b * 256 + tid] / PACE_);
    __syncthreads();
    for (int off = 1; off < 256; off <<= 1) {
        int v = 0;
        if (tid < 256) { v = cums[tid]; if (tid >= off) v += cums[tid - off]; }
        __syncthreads();
        if (tid < 256) cums[tid] = v;
        __syncthreads();
    }
    const int dec_len = min(cums[255], M_);
    if (tid < 128) {
        const int j = j0 + tid;
        int lo = 0, hi = 256;
        while (lo < hi) {
            const int mid = (lo + hi) >> 1;
            if (cums[mid] <= j) lo = mid + 1; else hi = mid;
        }
        ids[tid] = min(lo, 255);
        dec_mask[b * M_ + j] = (j < dec_len) ? 1.f : 0.f;
    }
    __syncthreads();

    const int w = tid >> 6, l = tid & 63;
    const int q = l >> 4, lm = l & 15;
    const int row = ids[w * 16 + lm];
    const float* apf = enc_out + (size_t)(b * 256 + row) * D_ + q * 8;

    // A: raw enc_out f32 -> bf16 (12 chunks)
    bf16x8 areg[D_ / 32];
#pragma unroll
    for (int c = 0; c < D_ / 32; c++) {
        const float4 v0 = *(const float4*)(apf + c * 32);
        const float4 v1 = *(const float4*)(apf + c * 32 + 4);
        bf16x8 t;
        unsigned short* tp = (unsigned short*)&t;
        tp[0] = f2bf(v0.x); tp[1] = f2bf(v0.y); tp[2] = f2bf(v0.z); tp[3] = f2bf(v0.w);
        tp[4] = f2bf(v1.x); tp[5] = f2bf(v1.y); tp[6] = f2bf(v1.z); tp[7] = f2bf(v1.w);
        areg[c] = t;
    }

    f32x4_ acc[5];
#pragma unroll
    for (int nt = 0; nt < 5; nt++)
#pragma unroll
        for (int k = 0; k < 4; k++) acc[nt][k] = 0.f;

    // B-stream ping-pong (distance 1)
    bf16x8 bvA[5], bvB[5];
#pragma unroll
    for (int nt = 0; nt < 5; nt++)
        bvA[nt] = *(const bf16x8*)(pwb + (((size_t)0 * 5 + nt) << 9) + l * 8);
    for (int cc = 0; cc < D_ / 32; cc += 2) {
#pragma unroll
        for (int nt = 0; nt < 5; nt++)
            bvB[nt] = *(const bf16x8*)(pwb + (((size_t)(cc + 1) * 5 + nt) << 9) + l * 8);
        __builtin_amdgcn_sched_barrier(0);
#pragma unroll
        for (int nt = 0; nt < 5; nt++)
            acc[nt] = MFMA16(areg[cc], bvA[nt], acc[nt]);
        if (cc + 2 < D_ / 32) {
#pragma unroll
            for (int nt = 0; nt < 5; nt++)
                bvA[nt] = *(const bf16x8*)(pwb + (((size_t)(cc + 2) * 5 + nt) << 9) + l * 8);
        }
        __builtin_amdgcn_sched_barrier(0);
#pragma unroll
        for (int nt = 0; nt < 5; nt++)
            acc[nt] = MFMA16(areg[cc + 1], bvB[nt], acc[nt]);
    }

    // epilogue: + rank-3 pitch term, mask, bias
    float ptv[4][3];
    float msk[4];
#pragma unroll
    for (int r = 0; r < 4; r++) {
        const int jr = j0 + w * 16 + q * 4 + r;
        msk[r] = (jr < dec_len) ? 1.f : 0.f;
        const int rr = ids[w * 16 + q * 4 + r];
#pragma unroll
        for (int k = 0; k < 3; k++) {
            const int t2 = rr - 1 + k;
            ptv[r][k] = (t2 >= 0 && t2 < 256) ? pt[b * 256 + t2] : 0.f;
        }
    }
#pragma unroll
    for (int nt = 0; nt < 5; nt++) {
        const int n = nt * 16 + lm;
        const float pk0 = Pc[n], pk1 = Pc[80 + n], pk2 = Pc[160 + n];
        const float p0v = Pc[240 + n];
        const float bb = pb[n];
#pragma unroll
        for (int r = 0; r < 4; r++) {
            const int j = j0 + w * 16 + q * 4 + r;
            const float term = fmaf(pk0, ptv[r][0],
                               fmaf(pk1, ptv[r][1],
                               fmaf(pk2, ptv[r][2], p0v)));
            mel[((size_t)b * M_ + j) * NMEL_ + n] = msk[r] * (acc[nt][r] + term) + bb;
        }
    }
}

// ---------------------------------------------------------------------------
extern "C" void kernel_launch(void* const* d_in, const int* in_sizes, int n_in,
                              void* d_out, int out_size, void* d_ws, size_t ws_size,
                              hipStream_t stream)
{
    const float* enc_out   = (const float*)d_in[0];
    const float* enc_mask  = (const float*)d_in[1];
    const float* pitch_tgt = (const float*)d_in[2];
    const int*   durations = (const int*)d_in[3];

    const float* dur_c0_w = (const float*)d_in[4];
    const float* dur_c0_b = (const float*)d_in[5];
    const float* dur_n0_g = (const float*)d_in[6];
    const float* dur_n0_b = (const float*)d_in[7];
    const float* dur_c1_w = (const float*)d_in[8];
    const float* dur_c1_b = (const float*)d_in[9];
    const float* dur_n1_g = (const float*)d_in[10];
    const float* dur_n1_b = (const float*)d_in[11];
    const float* dur_fc_w = (const float*)d_in[12];
    const float* dur_fc_b = (const float*)d_in[13];

    const float* pit_c0_w = (const float*)d_in[14];
    const float* pit_c0_b = (const float*)d_in[15];
    const float* pit_n0_g = (const float*)d_in[16];
    const float* pit_n0_b = (const float*)d_in[17];
    const float* pit_c1_w = (const float*)d_in[18];
    const float* pit_c1_b = (const float*)d_in[19];
    const float* pit_n1_g = (const float*)d_in[20];
    const float* pit_n1_b = (const float*)d_in[21];
    const float* pit_fc_w = (const float*)d_in[22];
    const float* pit_fc_b = (const float*)d_in[23];

    const float* pemb_w = (const float*)d_in[24];
    const float* pemb_b = (const float*)d_in[25];
    const float* proj_w = (const float*)d_in[26];
    const float* proj_b = (const float*)d_in[27];

    // Output slices (flat, in return order), all fp32.
    float* out       = (float*)d_out;
    float* mel_out   = out;                                   // [B,M,NMEL]
    float* dec_mask  = mel_out + (size_t)B_ * M_ * NMEL_;     // [B,M,1]
    float* dur_pred  = dec_mask + (size_t)B_ * M_;            // [B,T]
    float* log_dur   = dur_pred + (size_t)B_ * T_;            // [B,T]
    float* pitch_prd = log_dur + (size_t)B_ * T_;             // [B,T]

    // Workspace layout (~2.8 MiB)
    char* wp = (char*)d_ws;
    unsigned short* p0d  = (unsigned short*)wp; wp += (size_t)3 * F_ * D_ * 2;  // conv0 w dur
    unsigned short* p0p  = (unsigned short*)wp; wp += (size_t)3 * F_ * D_ * 2;  // conv0 w pitch
    unsigned short* p1d  = (unsigned short*)wp; wp += (size_t)3 * F_ * F_ * 2;  // conv1 w dur
    unsigned short* p1p  = (unsigned short*)wp; wp += (size_t)3 * F_ * F_ * 2;  // conv1 w pitch
    unsigned short* pwb  = (unsigned short*)wp; wp += (size_t)5 * 12 * 512 * 2; // proj packed
    float*          Pc   = (float*)wp;                                          // [4][80]

    // 1: prep (rank-3 pitch precompute + 3x weight repack) — 497 blocks
    prep_kernel<<<PREP_BLOCKS, dim3(256), 0, stream>>>(
        pemb_w, pemb_b,
        proj_w, pwb, Pc,
        dur_c0_w, pit_c0_w, p0d, p0p,
        dur_c1_w, pit_c1_w, p1d, p1p);

    // 2: full predictors (32-row tiles, 256 blocks) ∥ mel gather-GEMM (256)
    mega_kernel<<<512, dim3(512), 0, stream>>>(
        enc_out, enc_mask,
        p0d, p0p, dur_c0_b, pit_c0_b,
        dur_n0_g, dur_n0_b, pit_n0_g, pit_n0_b,
        p1d, p1p, dur_c1_b, pit_c1_b,
        dur_n1_g, dur_n1_b, pit_n1_g, pit_n1_b,
        dur_fc_w, pit_fc_w, dur_fc_b, pit_fc_b,
        log_dur, pitch_prd, dur_pred,
        durations, pitch_tgt, Pc, pwb, proj_b,
        dec_mask, mel_out);
}

// Round 10
// 168.464 us; speedup vs baseline: 1.0034x; 1.0034x over previous
//
#include <hip/hip_runtime.h>
#include <math.h>

// Problem constants (from reference)
constexpr int B_ = 16, T_ = 256, D_ = 384, M_ = 2048, F_ = 256, NMEL_ = 80;
constexpr float PACE_ = 1.0f, MAXDUR_ = 75.0f;
constexpr int R_ = B_ * T_;  // 4096 total rows

typedef __attribute__((ext_vector_type(8))) short bf16x8;
typedef __attribute__((ext_vector_type(4))) float f32x4_;

static __device__ __forceinline__ unsigned short f2bf(float x) {
    union { float f; unsigned int u; } v; v.f = x;
    const unsigned int r = v.u + 0x7fffu + ((v.u >> 16) & 1u);  // RNE
    return (unsigned short)(r >> 16);
}

// ---------------------------------------------------------------------------
// Repack conv weight w[F_,CIN,3] fp32 -> bf16 16x16x32 B-fragment order:
//   p[ ((k*(F_/16) + fn)*(CIN/32) + c)*512 + lane*8 + j ]
//     = w[f = fn*16+(lane&15)][d = c*32+(lane>>4)*8+j][k]
// ---------------------------------------------------------------------------
template <int CIN>
static __device__ __forceinline__ void repack_dev(
    int gid, const float* __restrict__ w, unsigned short* __restrict__ p)
{
    constexpr int NC = CIN / 32;
    const int lane = gid & 63;
    int rest = gid >> 6;
    const int c = rest % NC;  rest /= NC;
    const int fn = rest % (F_ / 16);
    const int k  = rest / (F_ / 16);
    const int f = fn * 16 + (lane & 15);
    const int d = c * 32 + (lane >> 4) * 8;
    uint4 o;
    unsigned short* op = (unsigned short*)&o;
#pragma unroll
    for (int j = 0; j < 8; j++)
        op[j] = f2bf(w[((size_t)f * CIN + d + j) * 3 + k]);
    ((uint4*)p)[gid] = o;
}

// ---------------------------------------------------------------------------
// PREP kernel (blockIdx-partitioned, all sections independent):
//   [0,2)      pitch rank-3 precompute Pc (replaces the old pitch_add pass)
//   [2,17)     repack proj_w -> pwb
//   [17,305)   repack conv0 weights (dur, pitch)
//   [305,497)  repack conv1 weights (dur, pitch)
// regulate lives in the mel blocks of mega.
// ---------------------------------------------------------------------------
constexpr int PP_BLK = 2;
constexpr int PJ_BLK = 15;                      // 3840/256
constexpr int R0_BLK = 3 * F_ * D_ / 8 / 256;   // 144
constexpr int R1_BLK = 3 * F_ * F_ / 8 / 256;   // 96
constexpr int PREP_BLOCKS = PP_BLK + PJ_BLK + 2 * R0_BLK + 2 * R1_BLK;  // 497

__global__ __launch_bounds__(256) void prep_kernel(
    const float* __restrict__ we, const float* __restrict__ be,
    const float* __restrict__ projw, unsigned short* __restrict__ pwb,
    float* __restrict__ Pc,
    const float* __restrict__ c0wd, const float* __restrict__ c0wp,
    unsigned short* __restrict__ p0d, unsigned short* __restrict__ p0p,
    const float* __restrict__ c1wd, const float* __restrict__ c1wp,
    unsigned short* __restrict__ p1d, unsigned short* __restrict__ p1p)
{
    const int bx = blockIdx.x, tid = threadIdx.x;
    if (bx < PP_BLK) {
        // Pc[k*80+n]: k<3 -> sum_d proj[n,d]*we[d*3+k]; k=3 -> sum_d proj[n,d]*be[d]
        const int gid = bx * 256 + tid;   // over 320
        if (gid < 320) {
            const int n = gid % 80;
            const int k = gid / 80;
            const float* pr = projw + (size_t)n * D_;
            float s = 0.f;
            if (k < 3) {
#pragma unroll 4
                for (int d = 0; d < D_; d++) s = fmaf(pr[d], we[d * 3 + k], s);
            } else {
#pragma unroll 4
                for (int d = 0; d < D_; d++) s = fmaf(pr[d], be[d], s);
            }
            Pc[k * 80 + n] = s;
        }
    } else if (bx < PP_BLK + PJ_BLK) {
        const int gid = (bx - PP_BLK) * 256 + tid;  // over 3840
        const int lane = gid & 63;
        const int rest = gid >> 6;
        const int nt = rest % 5;
        const int c  = rest / 5;
        const int n = nt * 16 + (lane & 15);
        const int k = c * 32 + (lane >> 4) * 8;
        uint4 o;
        unsigned short* op = (unsigned short*)&o;
#pragma unroll
        for (int j = 0; j < 8; j++)
            op[j] = f2bf(projw[(size_t)n * D_ + k + j]);
        ((uint4*)pwb)[gid] = o;
    } else if (bx < PP_BLK + PJ_BLK + 2 * R0_BLK) {
        const int i = bx - (PP_BLK + PJ_BLK);
        const int sel = (i >= R0_BLK) ? 1 : 0;
        const int gid = (i - sel * R0_BLK) * 256 + tid;
        repack_dev<D_>(gid, sel ? c0wp : c0wd, sel ? p0p : p0d);
    } else {
        const int i = bx - (PP_BLK + PJ_BLK + 2 * R0_BLK);
        const int sel = (i >= R1_BLK) ? 1 : 0;
        const int gid = (i - sel * R1_BLK) * 256 + tid;
        repack_dev<F_>(gid, sel ? c1wp : c1wd, sel ? p1p : p1d);
    }
}

// ---------------------------------------------------------------------------
// Fully fused predictor, 32 output rows / 512 threads (8 waves) per block
// (R8 structure, byte-identical): conv0+ReLU+LN0 over 48 h-rows -> h in LDS
// -> conv1+ReLU+LN1+FC. Wave w owns channels w*32..w*32+31. B ping-pong +
// sched_barrier(0). __launch_bounds__(512,4).
// ---------------------------------------------------------------------------
constexpr int LDX_ = D_ + 8;   // 392, input stage stride (bf16)
constexpr int LDH_ = F_ + 8;   // 264, h stride (bf16)
constexpr int XS_BYTES = 50 * LDX_ * 2;                 // 39200 (> 48*LDH_*2)
constexpr int SMEM_A = XS_BYTES + 2 * 8 * 48 * 4;       // + reds/redq = 42272

#define MFMA16(a, b, c) __builtin_amdgcn_mfma_f32_16x16x32_bf16(a, b, c, 0, 0, 0)

static __device__ __forceinline__ void predictor_body(
    const int bx, char* smem,
    const float* __restrict__ x, const float* __restrict__ imask,
    const unsigned short* __restrict__ pw0, const float* __restrict__ b0,
    const float* __restrict__ g0, const float* __restrict__ be0,
    const unsigned short* __restrict__ pw1, const float* __restrict__ b1,
    const float* __restrict__ g1, const float* __restrict__ be1,
    const float* __restrict__ fw, const float* __restrict__ fbp,
    float* __restrict__ pred, float* __restrict__ durpred)
{
    unsigned short* xs = (unsigned short*)smem;           // [50][LDX_]
    unsigned short* hs = (unsigned short*)smem;           // [48][LDH_] (reuse)
    float* reds = (float*)(smem + XS_BYTES);              // [8][48]
    float* redq = reds + 8 * 48;

    const int r0  = bx * 32;          // 32-row tiles never cross a batch
    const int bb  = r0 >> 8;
    const int tl  = r0 & 255;
    const int tid = threadIdx.x;

    // ---- stage input rows tl-9 .. tl+40 (50 rows), masked, fp32->bf16
#pragma unroll
    for (int k = 0; k < 5; k++) {
        const int i = k * 512 + tid;
        if (k == 4 && tid >= 352) break;
        const int row = i / (D_ / 8);
        const int dd  = (i - row * (D_ / 8)) * 8;
        const int t   = tl - 9 + row;
        ushort4 o0 = {0, 0, 0, 0}, o1 = {0, 0, 0, 0};
        if (t >= 0 && t < 256) {
            const float m = imask[bb * 256 + t];
            const float* xr = x + (size_t)(bb * 256 + t) * D_ + dd;
            const float4 v0 = *(const float4*)xr;
            const float4 v1 = *(const float4*)(xr + 4);
            o0.x = f2bf(v0.x * m); o0.y = f2bf(v0.y * m);
            o0.z = f2bf(v0.z * m); o0.w = f2bf(v0.w * m);
            o1.x = f2bf(v1.x * m); o1.y = f2bf(v1.y * m);
            o1.z = f2bf(v1.z * m); o1.w = f2bf(v1.w * m);
        }
        *(ushort4*)(&xs[row * LDX_ + dd])     = o0;
        *(ushort4*)(&xs[row * LDX_ + dd + 4]) = o1;
    }
    __syncthreads();

    const int w = tid >> 6, l = tid & 63;     // w in [0,8)
    const int q = l >> 4, lm = l & 15;
    const unsigned short* pwl0 = pw0 + l * 8;
    const unsigned short* pwl1 = pw1 + l * 8;

    // ===== conv0 over 48 h-rows (3 m-tiles), 2 nf/wave, ping-pong B =====
    f32x4_ acc0[3][2];
#pragma unroll
    for (int mt = 0; mt < 3; mt++)
#pragma unroll
        for (int i = 0; i < 2; i++)
#pragma unroll
            for (int k = 0; k < 4; k++) acc0[mt][i][k] = 0.f;

    {
        bf16x8 bA[2][3], bB[2][3];
#pragma unroll
        for (int i = 0; i < 2; i++)
#pragma unroll
            for (int tap = 0; tap < 3; tap++)
                bA[i][tap] = *(const bf16x8*)(
                    pwl0 + ((((size_t)tap * 16 + (w * 2 + i)) * 12 + 0) << 9));

        for (int cc = 0; cc < 12; cc += 2) {
            {   // even: prefetch cc+1 -> bB, compute cc with bA
#pragma unroll
                for (int i = 0; i < 2; i++)
#pragma unroll
                    for (int tap = 0; tap < 3; tap++)
                        bB[i][tap] = *(const bf16x8*)(
                            pwl0 + ((((size_t)tap * 16 + (w * 2 + i)) * 12 + cc + 1) << 9));
                __builtin_amdgcn_sched_barrier(0);
#pragma unroll
                for (int mt = 0; mt < 3; mt++) {
                    bf16x8 a[3];
#pragma unroll
                    for (int tap = 0; tap < 3; tap++)
                        a[tap] = *(const bf16x8*)(
                            &xs[(mt * 16 + lm + tap) * LDX_ + cc * 32 + q * 8]);
#pragma unroll
                    for (int i = 0; i < 2; i++)
#pragma unroll
                        for (int tap = 0; tap < 3; tap++)
                            acc0[mt][i] = MFMA16(a[tap], bA[i][tap], acc0[mt][i]);
                }
            }
            {   // odd: prefetch cc+2 -> bA, compute cc+1 with bB
                if (cc + 2 < 12) {
#pragma unroll
                    for (int i = 0; i < 2; i++)
#pragma unroll
                        for (int tap = 0; tap < 3; tap++)
                            bA[i][tap] = *(const bf16x8*)(
                                pwl0 + ((((size_t)tap * 16 + (w * 2 + i)) * 12 + cc + 2) << 9));
                }
                __builtin_amdgcn_sched_barrier(0);
#pragma unroll
                for (int mt = 0; mt < 3; mt++) {
                    bf16x8 a[3];
#pragma unroll
                    for (int tap = 0; tap < 3; tap++)
                        a[tap] = *(const bf16x8*)(
                            &xs[(mt * 16 + lm + tap) * LDX_ + (cc + 1) * 32 + q * 8]);
#pragma unroll
                    for (int i = 0; i < 2; i++)
#pragma unroll
                        for (int tap = 0; tap < 3; tap++)
                            acc0[mt][i] = MFMA16(a[tap], bB[i][tap], acc0[mt][i]);
                }
            }
        }
    }

    // bias+ReLU. C/D layout: col=lane&15 (f), row=(lane>>4)*4+reg
    float v0[3][2][4];
#pragma unroll
    for (int i = 0; i < 2; i++) {
        const float bs = b0[w * 32 + i * 16 + lm];
#pragma unroll
        for (int mt = 0; mt < 3; mt++)
#pragma unroll
            for (int r = 0; r < 4; r++)
                v0[mt][i][r] = fmaxf(acc0[mt][i][r] + bs, 0.f);
    }

    // LN0 partials: per-lane over 2 nf, shfl over 16 lm-lanes, LDS over 8 waves
    {
        float s[3][4], t2[3][4];
#pragma unroll
        for (int mt = 0; mt < 3; mt++)
#pragma unroll
            for (int r = 0; r < 4; r++) {
                s[mt][r]  = v0[mt][0][r] + v0[mt][1][r];
                t2[mt][r] = v0[mt][0][r] * v0[mt][0][r] + v0[mt][1][r] * v0[mt][1][r];
            }
#pragma unroll
        for (int off = 1; off <= 8; off <<= 1)
#pragma unroll
            for (int mt = 0; mt < 3; mt++)
#pragma unroll
                for (int r = 0; r < 4; r++) {
                    s[mt][r]  += __shfl_xor(s[mt][r], off);
                    t2[mt][r] += __shfl_xor(t2[mt][r], off);
                }
        if (lm == 0) {
#pragma unroll
            for (int mt = 0; mt < 3; mt++)
#pragma unroll
                for (int r = 0; r < 4; r++) {
                    reds[w * 48 + mt * 16 + q * 4 + r] = s[mt][r];
                    redq[w * 48 + mt * 16 + q * 4 + r] = t2[mt][r];
                }
        }
    }
    __syncthreads();   // also: all xs reads complete -> hs overwrite safe

    // normalize + write h into LDS (zero rows whose t is outside the batch)
    {
        float mu[3][4], rs[3][4];
#pragma unroll
        for (int mt = 0; mt < 3; mt++)
#pragma unroll
            for (int r = 0; r < 4; r++) {
                const int hr = mt * 16 + q * 4 + r;
                float ts = 0.f, tq = 0.f;
#pragma unroll
                for (int ww = 0; ww < 8; ww++) {
                    ts += reds[ww * 48 + hr];
                    tq += redq[ww * 48 + hr];
                }
                const float m_ = ts * (1.f / F_);
                mu[mt][r] = m_;
                rs[mt][r] = rsqrtf(tq * (1.f / F_) - m_ * m_ + 1e-5f);
            }
#pragma unroll
        for (int i = 0; i < 2; i++) {
            const int f = w * 32 + i * 16 + lm;
            const float gg = g0[f], bb2 = be0[f];
#pragma unroll
            for (int mt = 0; mt < 3; mt++)
#pragma unroll
                for (int r = 0; r < 4; r++) {
                    const int hr = mt * 16 + q * 4 + r;
                    const int t  = tl - 8 + hr;
                    const float o = (t >= 0 && t < 256)
                        ? (v0[mt][i][r] - mu[mt][r]) * rs[mt][r] * gg + bb2 : 0.f;
                    hs[hr * LDH_ + f] = f2bf(o);
                }
        }
    }
    __syncthreads();

    // ===== conv1 over 32 rows (2 m-tiles), 2 nf/wave, ping-pong B =====
    f32x4_ acc1[2][2];
#pragma unroll
    for (int mt = 0; mt < 2; mt++)
#pragma unroll
        for (int i = 0; i < 2; i++)
#pragma unroll
            for (int k = 0; k < 4; k++) acc1[mt][i][k] = 0.f;

    {
        bf16x8 bA[2][3], bB[2][3];
#pragma unroll
        for (int i = 0; i < 2; i++)
#pragma unroll
            for (int tap = 0; tap < 3; tap++)
                bA[i][tap] = *(const bf16x8*)(
                    pwl1 + ((((size_t)tap * 16 + (w * 2 + i)) * 8 + 0) << 9));

        for (int cc = 0; cc < 8; cc += 2) {
            {   // even
#pragma unroll
                for (int i = 0; i < 2; i++)
#pragma unroll
                    for (int tap = 0; tap < 3; tap++)
                        bB[i][tap] = *(const bf16x8*)(
                            pwl1 + ((((size_t)tap * 16 + (w * 2 + i)) * 8 + cc + 1) << 9));
                __builtin_amdgcn_sched_barrier(0);
#pragma unroll
                for (int mt = 0; mt < 2; mt++) {
                    bf16x8 a[3];
#pragma unroll
                    for (int tap = 0; tap < 3; tap++)
                        a[tap] = *(const bf16x8*)(
                            &hs[(mt * 16 + lm + 7 + tap) * LDH_ + cc * 32 + q * 8]);
#pragma unroll
                    for (int i = 0; i < 2; i++)
#pragma unroll
                        for (int tap = 0; tap < 3; tap++)
                            acc1[mt][i] = MFMA16(a[tap], bA[i][tap], acc1[mt][i]);
                }
            }
            {   // odd
                if (cc + 2 < 8) {
#pragma unroll
                    for (int i = 0; i < 2; i++)
#pragma unroll
                        for (int tap = 0; tap < 3; tap++)
                            bA[i][tap] = *(const bf16x8*)(
                                pwl1 + ((((size_t)tap * 16 + (w * 2 + i)) * 8 + cc + 2) << 9));
                }
                __builtin_amdgcn_sched_barrier(0);
#pragma unroll
                for (int mt = 0; mt < 2; mt++) {
                    bf16x8 a[3];
#pragma unroll
                    for (int tap = 0; tap < 3; tap++)
                        a[tap] = *(const bf16x8*)(
                            &hs[(mt * 16 + lm + 7 + tap) * LDH_ + (cc + 1) * 32 + q * 8]);
#pragma unroll
                    for (int i = 0; i < 2; i++)
#pragma unroll
                        for (int tap = 0; tap < 3; tap++)
                            acc1[mt][i] = MFMA16(a[tap], bB[i][tap], acc1[mt][i]);
                }
            }
        }
    }

    float v1[2][2][4];
#pragma unroll
    for (int i = 0; i < 2; i++) {
        const float bs = b1[w * 32 + i * 16 + lm];
#pragma unroll
        for (int mt = 0; mt < 2; mt++)
#pragma unroll
            for (int r = 0; r < 4; r++)
                v1[mt][i][r] = fmaxf(acc1[mt][i][r] + bs, 0.f);
    }

    // LN1 partials
    {
        float s[2][4], t2[2][4];
#pragma unroll
        for (int mt = 0; mt < 2; mt++)
#pragma unroll
            for (int r = 0; r < 4; r++) {
                s[mt][r]  = v1[mt][0][r] + v1[mt][1][r];
                t2[mt][r] = v1[mt][0][r] * v1[mt][0][r] + v1[mt][1][r] * v1[mt][1][r];
            }
#pragma unroll
        for (int off = 1; off <= 8; off <<= 1)
#pragma unroll
            for (int mt = 0; mt < 2; mt++)
#pragma unroll
                for (int r = 0; r < 4; r++) {
                    s[mt][r]  += __shfl_xor(s[mt][r], off);
                    t2[mt][r] += __shfl_xor(t2[mt][r], off);
                }
        __syncthreads();   // conv1's hs reads + LN0 reds reads done
        if (lm == 0) {
#pragma unroll
            for (int mt = 0; mt < 2; mt++)
#pragma unroll
                for (int r = 0; r < 4; r++) {
                    reds[w * 32 + mt * 16 + q * 4 + r] = s[mt][r];
                    redq[w * 32 + mt * 16 + q * 4 + r] = t2[mt][r];
                }
        }
    }
    __syncthreads();

    float mu1[2][4], rs1[2][4];
#pragma unroll
    for (int mt = 0; mt < 2; mt++)
#pragma unroll
        for (int r = 0; r < 4; r++) {
            const int or_ = mt * 16 + q * 4 + r;
            float ts = 0.f, tq = 0.f;
#pragma unroll
            for (int ww = 0; ww < 8; ww++) {
                ts += reds[ww * 32 + or_];
                tq += redq[ww * 32 + or_];
            }
            const float m_ = ts * (1.f / F_);
            mu1[mt][r] = m_;
            rs1[mt][r] = rsqrtf(tq * (1.f / F_) - m_ * m_ + 1e-5f);
        }

    // FC head: pred[row] = (dot(LN1(v1), fw) + fb) * mask[row]
    float fcp[2][4];
#pragma unroll
    for (int mt = 0; mt < 2; mt++)
#pragma unroll
        for (int r = 0; r < 4; r++) fcp[mt][r] = 0.f;
#pragma unroll
    for (int i = 0; i < 2; i++) {
        const int f = w * 32 + i * 16 + lm;
        const float gg = g1[f], bb2 = be1[f], wv = fw[f];
#pragma unroll
        for (int mt = 0; mt < 2; mt++)
#pragma unroll
            for (int r = 0; r < 4; r++)
                fcp[mt][r] += ((v1[mt][i][r] - mu1[mt][r]) * rs1[mt][r] * gg + bb2) * wv;
    }
#pragma unroll
    for (int off = 1; off <= 8; off <<= 1)
#pragma unroll
        for (int mt = 0; mt < 2; mt++)
#pragma unroll
            for (int r = 0; r < 4; r++) fcp[mt][r] += __shfl_xor(fcp[mt][r], off);
    __syncthreads();   // mu1/rs1 reads of reds complete
    if (lm == 0) {
#pragma unroll
        for (int mt = 0; mt < 2; mt++)
#pragma unroll
            for (int r = 0; r < 4; r++)
                reds[w * 32 + mt * 16 + q * 4 + r] = fcp[mt][r];
    }
    __syncthreads();
    if (tid < 32) {
        float tot = fbp[0];
#pragma unroll
        for (int ww = 0; ww < 8; ww++) tot += reds[ww * 32 + tid];
        const int row = r0 + tid;
        const float p = tot * imask[row];
        pred[row] = p;
        if (durpred) durpred[row] = fminf(fmaxf(expf(p) - 1.f, 0.f), MAXDUR_);
    }
}

// ---------------------------------------------------------------------------
// Launch 2: predictors (dur blocks 0..127, pitch 128..255) ∥ mel gather-GEMM
// (blocks 256..511), 512 threads each. Mel: self-contained regulate, A
// gathered from raw enc_out f32 -> bf16 PER-ITERATION (#pragma unroll 1 —
// no batched load arrays; R9's batched version spilled: VGPR 64, +24 MB
// scratch writes). Pitch conditioning via rank-3 epilogue (Pc).
// ---------------------------------------------------------------------------
__global__ __launch_bounds__(512, 4) void mega_kernel(
    const float* __restrict__ enc_out, const float* __restrict__ enc_mask,
    const unsigned short* __restrict__ p0d, const unsigned short* __restrict__ p0p,
    const float* __restrict__ c0b_d, const float* __restrict__ c0b_p,
    const float* __restrict__ g0_d, const float* __restrict__ be0_d,
    const float* __restrict__ g0_p, const float* __restrict__ be0_p,
    const unsigned short* __restrict__ p1d, const unsigned short* __restrict__ p1p,
    const float* __restrict__ c1b_d, const float* __restrict__ c1b_p,
    const float* __restrict__ g1_d, const float* __restrict__ be1_d,
    const float* __restrict__ g1_p, const float* __restrict__ be1_p,
    const float* __restrict__ fw_d, const float* __restrict__ fw_p,
    const float* __restrict__ fb_d, const float* __restrict__ fb_p,
    float* __restrict__ log_dur, float* __restrict__ pitch_prd,
    float* __restrict__ durpred,
    const int* __restrict__ dur, const float* __restrict__ pt,
    const float* __restrict__ Pc,
    const unsigned short* __restrict__ pwb,
    const float* __restrict__ pb,
    float* __restrict__ dec_mask, float* __restrict__ mel)
{
    __shared__ __align__(16) char smem[SMEM_A];
    const int bxx = blockIdx.x;
    if (bxx < 256) {
        const int z = bxx >> 7;
        predictor_body(bxx & 127, smem,
            enc_out, enc_mask,
            z ? p0p : p0d, z ? c0b_p : c0b_d,
            z ? g0_p : g0_d, z ? be0_p : be0_d,
            z ? p1p : p1d, z ? c1b_p : c1b_d,
            z ? g1_p : g1_d, z ? be1_p : be1_d,
            z ? fw_p : fw_d, z ? fb_p : fb_d,
            z ? pitch_prd : log_dur, z ? nullptr : durpred);
        return;
    }
    // ---- mel branch: 128 j-rows per block, self-contained regulate.
    int* cums = (int*)smem;          // [256]
    int* ids  = cums + 256;          // [128]
    const int i  = bxx - 256;
    const int b  = i >> 4;
    const int j0 = (i & 15) * 128;
    const int tid = threadIdx.x;

    if (tid < 256) cums[tid] = (int)rintf((float)dur[b * 256 + tid] / PACE_);
    __syncthreads();
    for (int off = 1; off < 256; off <<= 1) {
        int v = 0;
        if (tid < 256) { v = cums[tid]; if (tid >= off) v += cums[tid - off]; }
        __syncthreads();
        if (tid < 256) cums[tid] = v;
        __syncthreads();
    }
    const int dec_len = min(cums[255], M_);
    if (tid < 128) {
        const int j = j0 + tid;
        int lo = 0, hi = 256;
        while (lo < hi) {
            const int mid = (lo + hi) >> 1;
            if (cums[mid] <= j) lo = mid + 1; else hi = mid;
        }
        ids[tid] = min(lo, 255);
        dec_mask[b * M_ + j] = (j < dec_len) ? 1.f : 0.f;
    }
    __syncthreads();

    const int w = tid >> 6, l = tid & 63;
    const int q = l >> 4, lm = l & 15;
    const int row = ids[w * 16 + lm];
    const float* apf = enc_out + (size_t)(b * 256 + row) * D_ + q * 8;

    f32x4_ acc[5];
#pragma unroll
    for (int nt = 0; nt < 5; nt++)
#pragma unroll
        for (int k = 0; k < 4; k++) acc[nt][k] = 0.f;

    // Streamed GEMM: per iteration load ONE f32 A-chunk + 5 B-frags, convert,
    // MFMA. unroll 1 keeps the live set ~85 VGPR (no spill); 16 waves/CU TLP
    // hides the per-iteration L2/L3 latency.
#pragma unroll 1
    for (int c = 0; c < D_ / 32; c++) {
        const float4 v0 = *(const float4*)(apf + c * 32);
        const float4 v1 = *(const float4*)(apf + c * 32 + 4);
        bf16x8 bv0 = *(const bf16x8*)(pwb + (((size_t)c * 5 + 0) << 9) + l * 8);
        bf16x8 bv1 = *(const bf16x8*)(pwb + (((size_t)c * 5 + 1) << 9) + l * 8);
        bf16x8 bv2 = *(const bf16x8*)(pwb + (((size_t)c * 5 + 2) << 9) + l * 8);
        bf16x8 bv3 = *(const bf16x8*)(pwb + (((size_t)c * 5 + 3) << 9) + l * 8);
        bf16x8 bv4 = *(const bf16x8*)(pwb + (((size_t)c * 5 + 4) << 9) + l * 8);
        bf16x8 a;
        unsigned short* tp = (unsigned short*)&a;
        tp[0] = f2bf(v0.x); tp[1] = f2bf(v0.y); tp[2] = f2bf(v0.z); tp[3] = f2bf(v0.w);
        tp[4] = f2bf(v1.x); tp[5] = f2bf(v1.y); tp[6] = f2bf(v1.z); tp[7] = f2bf(v1.w);
        acc[0] = MFMA16(a, bv0, acc[0]);
        acc[1] = MFMA16(a, bv1, acc[1]);
        acc[2] = MFMA16(a, bv2, acc[2]);
        acc[3] = MFMA16(a, bv3, acc[3]);
        acc[4] = MFMA16(a, bv4, acc[4]);
    }

    // epilogue: + rank-3 pitch term, mask, bias
    float ptv[4][3];
    float msk[4];
#pragma unroll
    for (int r = 0; r < 4; r++) {
        const int jr = j0 + w * 16 + q * 4 + r;
        msk[r] = (jr < dec_len) ? 1.f : 0.f;
        const int rr = ids[w * 16 + q * 4 + r];
#pragma unroll
        for (int k = 0; k < 3; k++) {
            const int t2 = rr - 1 + k;
            ptv[r][k] = (t2 >= 0 && t2 < 256) ? pt[b * 256 + t2] : 0.f;
        }
    }
#pragma unroll
    for (int nt = 0; nt < 5; nt++) {
        const int n = nt * 16 + lm;
        const float pk0 = Pc[n], pk1 = Pc[80 + n], pk2 = Pc[160 + n];
        const float p0v = Pc[240 + n];
        const float bb = pb[n];
#pragma unroll
        for (int r = 0; r < 4; r++) {
            const int j = j0 + w * 16 + q * 4 + r;
            const float term = fmaf(pk0, ptv[r][0],
                               fmaf(pk1, ptv[r][1],
                               fmaf(pk2, ptv[r][2], p0v)));
            mel[((size_t)b * M_ + j) * NMEL_ + n] = msk[r] * (acc[nt][r] + term) + bb;
        }
    }
}

// ---------------------------------------------------------------------------
extern "C" void kernel_launch(void* const* d_in, const int* in_sizes, int n_in,
                              void* d_out, int out_size, void* d_ws, size_t ws_size,
                              hipStream_t stream)
{
    const float* enc_out   = (const float*)d_in[0];
    const float* enc_mask  = (const float*)d_in[1];
    const float* pitch_tgt = (const float*)d_in[2];
    const int*   durations = (const int*)d_in[3];

    const float* dur_c0_w = (const float*)d_in[4];
    const float* dur_c0_b = (const float*)d_in[5];
    const float* dur_n0_g = (const float*)d_in[6];
    const float* dur_n0_b = (const float*)d_in[7];
    const float* dur_c1_w = (const float*)d_in[8];
    const float* dur_c1_b = (const float*)d_in[9];
    const float* dur_n1_g = (const float*)d_in[10];
    const float* dur_n1_b = (const float*)d_in[11];
    const float* dur_fc_w = (const float*)d_in[12];
    const float* dur_fc_b = (const float*)d_in[13];

    const float* pit_c0_w = (const float*)d_in[14];
    const float* pit_c0_b = (const float*)d_in[15];
    const float* pit_n0_g = (const float*)d_in[16];
    const float* pit_n0_b = (const float*)d_in[17];
    const float* pit_c1_w = (const float*)d_in[18];
    const float* pit_c1_b = (const float*)d_in[19];
    const float* pit_n1_g = (const float*)d_in[20];
    const float* pit_n1_b = (const float*)d_in[21];
    const float* pit_fc_w = (const float*)d_in[22];
    const float* pit_fc_b = (const float*)d_in[23];

    const float* pemb_w = (const float*)d_in[24];
    const float* pemb_b = (const float*)d_in[25];
    const float* proj_w = (const float*)d_in[26];
    const float* proj_b = (const float*)d_in[27];

    // Output slices (flat, in return order), all fp32.
    float* out       = (float*)d_out;
    float* mel_out   = out;                                   // [B,M,NMEL]
    float* dec_mask  = mel_out + (size_t)B_ * M_ * NMEL_;     // [B,M,1]
    float* dur_pred  = dec_mask + (size_t)B_ * M_;            // [B,T]
    float* log_dur   = dur_pred + (size_t)B_ * T_;            // [B,T]
    float* pitch_prd = log_dur + (size_t)B_ * T_;             // [B,T]

    // Workspace layout (~2.8 MiB)
    char* wp = (char*)d_ws;
    unsigned short* p0d  = (unsigned short*)wp; wp += (size_t)3 * F_ * D_ * 2;  // conv0 w dur
    unsigned short* p0p  = (unsigned short*)wp; wp += (size_t)3 * F_ * D_ * 2;  // conv0 w pitch
    unsigned short* p1d  = (unsigned short*)wp; wp += (size_t)3 * F_ * F_ * 2;  // conv1 w dur
    unsigned short* p1p  = (unsigned short*)wp; wp += (size_t)3 * F_ * F_ * 2;  // conv1 w pitch
    unsigned short* pwb  = (unsigned short*)wp; wp += (size_t)5 * 12 * 512 * 2; // proj packed
    float*          Pc   = (float*)wp;                                          // [4][80]

    // 1: prep (rank-3 pitch precompute + 3x weight repack) — 497 blocks
    prep_kernel<<<PREP_BLOCKS, dim3(256), 0, stream>>>(
        pemb_w, pemb_b,
        proj_w, pwb, Pc,
        dur_c0_w, pit_c0_w, p0d, p0p,
        dur_c1_w, pit_c1_w, p1d, p1p);

    // 2: full predictors (32-row tiles, 256 blocks) ∥ mel gather-GEMM (256)
    mega_kernel<<<512, dim3(512), 0, stream>>>(
        enc_out, enc_mask,
        p0d, p0p, dur_c0_b, pit_c0_b,
        dur_n0_g, dur_n0_b, pit_n0_g, pit_n0_b,
        p1d, p1p, dur_c1_b, pit_c1_b,
        dur_n1_g, dur_n1_b, pit_n1_g, pit_n1_b,
        dur_fc_w, pit_fc_w, dur_fc_b, pit_fc_b,
        log_dur, pitch_prd, dur_pred,
        durations, pitch_tgt, Pc, pwb, proj_b,
        dec_mask, mel_out);
}

// Round 11
// 143.075 us; speedup vs baseline: 1.1815x; 1.1775x over previous
//
#include <hip/hip_runtime.h>
#include <math.h>

// Problem constants (from reference)
constexpr int B_ = 16, T_ = 256, D_ = 384, M_ = 2048, F_ = 256, NMEL_ = 80;
constexpr float PACE_ = 1.0f, MAXDUR_ = 75.0f;
constexpr int R_ = B_ * T_;  // 4096 total rows

typedef __attribute__((ext_vector_type(8))) short bf16x8;
typedef __attribute__((ext_vector_type(4))) float f32x4_;

static __device__ __forceinline__ unsigned short f2bf(float x) {
    union { float f; unsigned int u; } v; v.f = x;
    const unsigned int r = v.u + 0x7fffu + ((v.u >> 16) & 1u);  // RNE
    return (unsigned short)(r >> 16);
}

// ---------------------------------------------------------------------------
// Repack conv weight w[F_,CIN,3] fp32 -> bf16 16x16x32 B-fragment order:
//   p[ ((k*(F_/16) + fn)*(CIN/32) + c)*512 + lane*8 + j ]
//     = w[f = fn*16+(lane&15)][d = c*32+(lane>>4)*8+j][k]
// ---------------------------------------------------------------------------
template <int CIN>
static __device__ __forceinline__ void repack_dev(
    int gid, const float* __restrict__ w, unsigned short* __restrict__ p)
{
    constexpr int NC = CIN / 32;
    const int lane = gid & 63;
    int rest = gid >> 6;
    const int c = rest % NC;  rest /= NC;
    const int fn = rest % (F_ / 16);
    const int k  = rest / (F_ / 16);
    const int f = fn * 16 + (lane & 15);
    const int d = c * 32 + (lane >> 4) * 8;
    uint4 o;
    unsigned short* op = (unsigned short*)&o;
#pragma unroll
    for (int j = 0; j < 8; j++)
        op[j] = f2bf(w[((size_t)f * CIN + d + j) * 3 + k]);
    ((uint4*)p)[gid] = o;
}

// ---------------------------------------------------------------------------
// PREP mega-kernel (blockIdx-partitioned, all sections independent)
// ---------------------------------------------------------------------------
constexpr int PA_BLK = R_ * D_ / 8 / 256;       // 768 (8 elems/thread)
constexpr int RG_BLK = B_;                      // 16
constexpr int PJ_BLK = 15;                      // 3840/256
constexpr int R0_BLK = 3 * F_ * D_ / 8 / 256;   // 144
constexpr int R1_BLK = 3 * F_ * F_ / 8 / 256;   // 96
constexpr int PREP_BLOCKS = PA_BLK + RG_BLK + PJ_BLK + 2 * R0_BLK + 2 * R1_BLK;

__global__ __launch_bounds__(256) void prep_kernel(
    const float* __restrict__ enc_out, const float* __restrict__ pt,
    const float* __restrict__ we, const float* __restrict__ be,
    const int* __restrict__ dur, int* __restrict__ idx_out,
    float* __restrict__ dec_mask,
    const float* __restrict__ projw, unsigned short* __restrict__ pwb,
    const float* __restrict__ c0wd, const float* __restrict__ c0wp,
    unsigned short* __restrict__ p0d, unsigned short* __restrict__ p0p,
    const float* __restrict__ c1wd, const float* __restrict__ c1wp,
    unsigned short* __restrict__ p1d, unsigned short* __restrict__ p1p,
    unsigned short* __restrict__ encb)
{
    __shared__ int cums[T_];
    const int bx = blockIdx.x, tid = threadIdx.x;
    if (bx < PA_BLK) {
        // 8 consecutive d per thread (D_%8==0 so all 8 share one (b,t))
        const int gid = bx * 256 + tid;
        const int e  = gid * 8;
        const int bt = e / D_;
        const int d0 = e - bt * D_;
        const int t = bt % T_, b = bt / T_;
        float ptv[3];
#pragma unroll
        for (int k = 0; k < 3; k++) {
            const int t2 = t - 1 + k;
            ptv[k] = (t2 >= 0 && t2 < T_) ? pt[b * T_ + t2] : 0.f;
        }
        const float4 e0 = *(const float4*)(enc_out + e);
        const float4 e1 = *(const float4*)(enc_out + e + 4);
        const float ev[8] = {e0.x, e0.y, e0.z, e0.w, e1.x, e1.y, e1.z, e1.w};
        uint4 o;
        unsigned short* op = (unsigned short*)&o;
#pragma unroll
        for (int j = 0; j < 8; j++) {
            float s = be[d0 + j];
#pragma unroll
            for (int k = 0; k < 3; k++)
                s = fmaf(we[(d0 + j) * 3 + k], ptv[k], s);
            op[j] = f2bf(ev[j] + s);
        }
        ((uint4*)encb)[gid] = o;
    } else if (bx < PA_BLK + RG_BLK) {
        const int b = bx - PA_BLK, t = tid;
        cums[t] = (int)rintf((float)dur[b * T_ + t] / PACE_);
        __syncthreads();
        for (int off = 1; off < T_; off <<= 1) {
            int v = cums[t];
            if (t >= off) v += cums[t - off];
            __syncthreads();
            cums[t] = v;
            __syncthreads();
        }
        const int dec_len = min(cums[T_ - 1], M_);
#pragma unroll
        for (int r = 0; r < M_ / T_; r++) {
            const int j = r * T_ + t;
            int lo = 0, hi = T_;
            while (lo < hi) {
                const int mid = (lo + hi) >> 1;
                if (cums[mid] <= j) lo = mid + 1; else hi = mid;
            }
            idx_out[b * M_ + j]  = min(lo, T_ - 1);
            dec_mask[b * M_ + j] = (j < dec_len) ? 1.f : 0.f;
        }
    } else if (bx < PA_BLK + RG_BLK + PJ_BLK) {
        const int gid = (bx - PA_BLK - RG_BLK) * 256 + tid;  // over 3840
        const int lane = gid & 63;
        const int rest = gid >> 6;
        const int nt = rest % 5;
        const int c  = rest / 5;
        const int n = nt * 16 + (lane & 15);
        const int k = c * 32 + (lane >> 4) * 8;
        uint4 o;
        unsigned short* op = (unsigned short*)&o;
#pragma unroll
        for (int j = 0; j < 8; j++)
            op[j] = f2bf(projw[(size_t)n * D_ + k + j]);
        ((uint4*)pwb)[gid] = o;
    } else if (bx < PA_BLK + RG_BLK + PJ_BLK + 2 * R0_BLK) {
        const int i = bx - (PA_BLK + RG_BLK + PJ_BLK);
        const int sel = (i >= R0_BLK) ? 1 : 0;
        const int gid = (i - sel * R0_BLK) * 256 + tid;
        repack_dev<D_>(gid, sel ? c0wp : c0wd, sel ? p0p : p0d);
    } else {
        const int i = bx - (PA_BLK + RG_BLK + PJ_BLK + 2 * R0_BLK);
        const int sel = (i >= R1_BLK) ? 1 : 0;
        const int gid = (i - sel * R1_BLK) * 256 + tid;
        repack_dev<F_>(gid, sel ? c1wp : c1wd, sel ? p1p : p1d);
    }
}

// ---------------------------------------------------------------------------
// Fully fused predictor, 32 output rows / 512 threads (8 waves) per block:
// conv0+ReLU+LN0 over 48 h-rows (halo recomputed) -> h in LDS ->
// conv1+ReLU+LN1+FC over rows tl..tl+31. Wave w owns channels w*32..w*32+31
// (2 nf-tiles). B-fragments distance-1 ping-pong + sched_barrier(0).
// __launch_bounds__(512,4): 128-VGPR cap -> 2 blocks/CU (16 waves).
// (R8 configuration — best measured: 145.4 µs.)
// ---------------------------------------------------------------------------
constexpr int LDX_ = D_ + 8;   // 392, input stage stride (bf16)
constexpr int LDH_ = F_ + 8;   // 264, h stride (bf16)
constexpr int XS_BYTES = 50 * LDX_ * 2;                 // 39200 (> 48*LDH_*2)
constexpr int SMEM_A = XS_BYTES + 2 * 8 * 48 * 4;       // + reds/redq = 42272

#define MFMA16(a, b, c) __builtin_amdgcn_mfma_f32_16x16x32_bf16(a, b, c, 0, 0, 0)

static __device__ __forceinline__ void predictor_body(
    const int bx, char* smem,
    const float* __restrict__ x, const float* __restrict__ imask,
    const unsigned short* __restrict__ pw0, const float* __restrict__ b0,
    const float* __restrict__ g0, const float* __restrict__ be0,
    const unsigned short* __restrict__ pw1, const float* __restrict__ b1,
    const float* __restrict__ g1, const float* __restrict__ be1,
    const float* __restrict__ fw, const float* __restrict__ fbp,
    float* __restrict__ pred, float* __restrict__ durpred)
{
    unsigned short* xs = (unsigned short*)smem;           // [50][LDX_]
    unsigned short* hs = (unsigned short*)smem;           // [48][LDH_] (reuse)
    float* reds = (float*)(smem + XS_BYTES);              // [8][48]
    float* redq = reds + 8 * 48;

    const int r0  = bx * 32;          // 32-row tiles never cross a batch
    const int bb  = r0 >> 8;
    const int tl  = r0 & 255;
    const int tid = threadIdx.x;

    // ---- stage input rows tl-9 .. tl+40 (50 rows), masked, fp32->bf16
    // 50*48 = 2400 items = 4*512 + 352
#pragma unroll
    for (int k = 0; k < 5; k++) {
        const int i = k * 512 + tid;
        if (k == 4 && tid >= 352) break;
        const int row = i / (D_ / 8);
        const int dd  = (i - row * (D_ / 8)) * 8;
        const int t   = tl - 9 + row;
        ushort4 o0 = {0, 0, 0, 0}, o1 = {0, 0, 0, 0};
        if (t >= 0 && t < 256) {
            const float m = imask[bb * 256 + t];
            const float* xr = x + (size_t)(bb * 256 + t) * D_ + dd;
            const float4 v0 = *(const float4*)xr;
            const float4 v1 = *(const float4*)(xr + 4);
            o0.x = f2bf(v0.x * m); o0.y = f2bf(v0.y * m);
            o0.z = f2bf(v0.z * m); o0.w = f2bf(v0.w * m);
            o1.x = f2bf(v1.x * m); o1.y = f2bf(v1.y * m);
            o1.z = f2bf(v1.z * m); o1.w = f2bf(v1.w * m);
        }
        *(ushort4*)(&xs[row * LDX_ + dd])     = o0;
        *(ushort4*)(&xs[row * LDX_ + dd + 4]) = o1;
    }
    __syncthreads();

    const int w = tid >> 6, l = tid & 63;     // w in [0,8)
    const int q = l >> 4, lm = l & 15;
    const unsigned short* pwl0 = pw0 + l * 8;
    const unsigned short* pwl1 = pw1 + l * 8;

    // ===== conv0 over 48 h-rows (3 m-tiles), 2 nf/wave, ping-pong B =====
    f32x4_ acc0[3][2];
#pragma unroll
    for (int mt = 0; mt < 3; mt++)
#pragma unroll
        for (int i = 0; i < 2; i++)
#pragma unroll
            for (int k = 0; k < 4; k++) acc0[mt][i][k] = 0.f;

    {
        bf16x8 bA[2][3], bB[2][3];
#pragma unroll
        for (int i = 0; i < 2; i++)
#pragma unroll
            for (int tap = 0; tap < 3; tap++)
                bA[i][tap] = *(const bf16x8*)(
                    pwl0 + ((((size_t)tap * 16 + (w * 2 + i)) * 12 + 0) << 9));

        for (int cc = 0; cc < 12; cc += 2) {
            {   // even: prefetch cc+1 -> bB, compute cc with bA
#pragma unroll
                for (int i = 0; i < 2; i++)
#pragma unroll
                    for (int tap = 0; tap < 3; tap++)
                        bB[i][tap] = *(const bf16x8*)(
                            pwl0 + ((((size_t)tap * 16 + (w * 2 + i)) * 12 + cc + 1) << 9));
                __builtin_amdgcn_sched_barrier(0);
#pragma unroll
                for (int mt = 0; mt < 3; mt++) {
                    bf16x8 a[3];
#pragma unroll
                    for (int tap = 0; tap < 3; tap++)
                        a[tap] = *(const bf16x8*)(
                            &xs[(mt * 16 + lm + tap) * LDX_ + cc * 32 + q * 8]);
#pragma unroll
                    for (int i = 0; i < 2; i++)
#pragma unroll
                        for (int tap = 0; tap < 3; tap++)
                            acc0[mt][i] = MFMA16(a[tap], bA[i][tap], acc0[mt][i]);
                }
            }
            {   // odd: prefetch cc+2 -> bA, compute cc+1 with bB
                if (cc + 2 < 12) {
#pragma unroll
                    for (int i = 0; i < 2; i++)
#pragma unroll
                        for (int tap = 0; tap < 3; tap++)
                            bA[i][tap] = *(const bf16x8*)(
                                pwl0 + ((((size_t)tap * 16 + (w * 2 + i)) * 12 + cc + 2) << 9));
                }
                __builtin_amdgcn_sched_barrier(0);
#pragma unroll
                for (int mt = 0; mt < 3; mt++) {
                    bf16x8 a[3];
#pragma unroll
                    for (int tap = 0; tap < 3; tap++)
                        a[tap] = *(const bf16x8*)(
                            &xs[(mt * 16 + lm + tap) * LDX_ + (cc + 1) * 32 + q * 8]);
#pragma unroll
                    for (int i = 0; i < 2; i++)
#pragma unroll
                        for (int tap = 0; tap < 3; tap++)
                            acc0[mt][i] = MFMA16(a[tap], bB[i][tap], acc0[mt][i]);
                }
            }
        }
    }

    // bias+ReLU. C/D layout: col=lane&15 (f), row=(lane>>4)*4+reg
    float v0[3][2][4];
#pragma unroll
    for (int i = 0; i < 2; i++) {
        const float bs = b0[w * 32 + i * 16 + lm];
#pragma unroll
        for (int mt = 0; mt < 3; mt++)
#pragma unroll
            for (int r = 0; r < 4; r++)
                v0[mt][i][r] = fmaxf(acc0[mt][i][r] + bs, 0.f);
    }

    // LN0 partials: per-lane over 2 nf, shfl over 16 lm-lanes, LDS over 8 waves
    {
        float s[3][4], t2[3][4];
#pragma unroll
        for (int mt = 0; mt < 3; mt++)
#pragma unroll
            for (int r = 0; r < 4; r++) {
                s[mt][r]  = v0[mt][0][r] + v0[mt][1][r];
                t2[mt][r] = v0[mt][0][r] * v0[mt][0][r] + v0[mt][1][r] * v0[mt][1][r];
            }
#pragma unroll
        for (int off = 1; off <= 8; off <<= 1)
#pragma unroll
            for (int mt = 0; mt < 3; mt++)
#pragma unroll
                for (int r = 0; r < 4; r++) {
                    s[mt][r]  += __shfl_xor(s[mt][r], off);
                    t2[mt][r] += __shfl_xor(t2[mt][r], off);
                }
        if (lm == 0) {
#pragma unroll
            for (int mt = 0; mt < 3; mt++)
#pragma unroll
                for (int r = 0; r < 4; r++) {
                    reds[w * 48 + mt * 16 + q * 4 + r] = s[mt][r];
                    redq[w * 48 + mt * 16 + q * 4 + r] = t2[mt][r];
                }
        }
    }
    __syncthreads();   // also: all xs reads complete -> hs overwrite safe

    // normalize + write h into LDS (zero rows whose t is outside the batch)
    {
        float mu[3][4], rs[3][4];
#pragma unroll
        for (int mt = 0; mt < 3; mt++)
#pragma unroll
            for (int r = 0; r < 4; r++) {
                const int hr = mt * 16 + q * 4 + r;
                float ts = 0.f, tq = 0.f;
#pragma unroll
                for (int ww = 0; ww < 8; ww++) {
                    ts += reds[ww * 48 + hr];
                    tq += redq[ww * 48 + hr];
                }
                const float m_ = ts * (1.f / F_);
                mu[mt][r] = m_;
                rs[mt][r] = rsqrtf(tq * (1.f / F_) - m_ * m_ + 1e-5f);
            }
#pragma unroll
        for (int i = 0; i < 2; i++) {
            const int f = w * 32 + i * 16 + lm;
            const float gg = g0[f], bb2 = be0[f];
#pragma unroll
            for (int mt = 0; mt < 3; mt++)
#pragma unroll
                for (int r = 0; r < 4; r++) {
                    const int hr = mt * 16 + q * 4 + r;
                    const int t  = tl - 8 + hr;
                    const float o = (t >= 0 && t < 256)
                        ? (v0[mt][i][r] - mu[mt][r]) * rs[mt][r] * gg + bb2 : 0.f;
                    hs[hr * LDH_ + f] = f2bf(o);
                }
        }
    }
    __syncthreads();

    // ===== conv1 over 32 rows (2 m-tiles), 2 nf/wave, ping-pong B =====
    f32x4_ acc1[2][2];
#pragma unroll
    for (int mt = 0; mt < 2; mt++)
#pragma unroll
        for (int i = 0; i < 2; i++)
#pragma unroll
            for (int k = 0; k < 4; k++) acc1[mt][i][k] = 0.f;

    {
        bf16x8 bA[2][3], bB[2][3];
#pragma unroll
        for (int i = 0; i < 2; i++)
#pragma unroll
            for (int tap = 0; tap < 3; tap++)
                bA[i][tap] = *(const bf16x8*)(
                    pwl1 + ((((size_t)tap * 16 + (w * 2 + i)) * 8 + 0) << 9));

        for (int cc = 0; cc < 8; cc += 2) {
            {   // even
#pragma unroll
                for (int i = 0; i < 2; i++)
#pragma unroll
                    for (int tap = 0; tap < 3; tap++)
                        bB[i][tap] = *(const bf16x8*)(
                            pwl1 + ((((size_t)tap * 16 + (w * 2 + i)) * 8 + cc + 1) << 9));
                __builtin_amdgcn_sched_barrier(0);
#pragma unroll
                for (int mt = 0; mt < 2; mt++) {
                    bf16x8 a[3];
#pragma unroll
                    for (int tap = 0; tap < 3; tap++)
                        a[tap] = *(const bf16x8*)(
                            &hs[(mt * 16 + lm + 7 + tap) * LDH_ + cc * 32 + q * 8]);
#pragma unroll
                    for (int i = 0; i < 2; i++)
#pragma unroll
                        for (int tap = 0; tap < 3; tap++)
                            acc1[mt][i] = MFMA16(a[tap], bA[i][tap], acc1[mt][i]);
                }
            }
            {   // odd
                if (cc + 2 < 8) {
#pragma unroll
                    for (int i = 0; i < 2; i++)
#pragma unroll
                        for (int tap = 0; tap < 3; tap++)
                            bA[i][tap] = *(const bf16x8*)(
                                pwl1 + ((((size_t)tap * 16 + (w * 2 + i)) * 8 + cc + 2) << 9));
                }
                __builtin_amdgcn_sched_barrier(0);
#pragma unroll
                for (int mt = 0; mt < 2; mt++) {
                    bf16x8 a[3];
#pragma unroll
                    for (int tap = 0; tap < 3; tap++)
                        a[tap] = *(const bf16x8*)(
                            &hs[(mt * 16 + lm + 7 + tap) * LDH_ + (cc + 1) * 32 + q * 8]);
#pragma unroll
                    for (int i = 0; i < 2; i++)
#pragma unroll
                        for (int tap = 0; tap < 3; tap++)
                            acc1[mt][i] = MFMA16(a[tap], bB[i][tap], acc1[mt][i]);
                }
            }
        }
    }

    float v1[2][2][4];
#pragma unroll
    for (int i = 0; i < 2; i++) {
        const float bs = b1[w * 32 + i * 16 + lm];
#pragma unroll
        for (int mt = 0; mt < 2; mt++)
#pragma unroll
            for (int r = 0; r < 4; r++)
                v1[mt][i][r] = fmaxf(acc1[mt][i][r] + bs, 0.f);
    }

    // LN1 partials
    {
        float s[2][4], t2[2][4];
#pragma unroll
        for (int mt = 0; mt < 2; mt++)
#pragma unroll
            for (int r = 0; r < 4; r++) {
                s[mt][r]  = v1[mt][0][r] + v1[mt][1][r];
                t2[mt][r] = v1[mt][0][r] * v1[mt][0][r] + v1[mt][1][r] * v1[mt][1][r];
            }
#pragma unroll
        for (int off = 1; off <= 8; off <<= 1)
#pragma unroll
            for (int mt = 0; mt < 2; mt++)
#pragma unroll
                for (int r = 0; r < 4; r++) {
                    s[mt][r]  += __shfl_xor(s[mt][r], off);
                    t2[mt][r] += __shfl_xor(t2[mt][r], off);
                }
        __syncthreads();   // conv1's hs reads + LN0 reds reads done
        if (lm == 0) {
#pragma unroll
            for (int mt = 0; mt < 2; mt++)
#pragma unroll
                for (int r = 0; r < 4; r++) {
                    reds[w * 32 + mt * 16 + q * 4 + r] = s[mt][r];
                    redq[w * 32 + mt * 16 + q * 4 + r] = t2[mt][r];
                }
        }
    }
    __syncthreads();

    float mu1[2][4], rs1[2][4];
#pragma unroll
    for (int mt = 0; mt < 2; mt++)
#pragma unroll
        for (int r = 0; r < 4; r++) {
            const int or_ = mt * 16 + q * 4 + r;
            float ts = 0.f, tq = 0.f;
#pragma unroll
            for (int ww = 0; ww < 8; ww++) {
                ts += reds[ww * 32 + or_];
                tq += redq[ww * 32 + or_];
            }
            const float m_ = ts * (1.f / F_);
            mu1[mt][r] = m_;
            rs1[mt][r] = rsqrtf(tq * (1.f / F_) - m_ * m_ + 1e-5f);
        }

    // FC head: pred[row] = (dot(LN1(v1), fw) + fb) * mask[row]
    float fcp[2][4];
#pragma unroll
    for (int mt = 0; mt < 2; mt++)
#pragma unroll
        for (int r = 0; r < 4; r++) fcp[mt][r] = 0.f;
#pragma unroll
    for (int i = 0; i < 2; i++) {
        const int f = w * 32 + i * 16 + lm;
        const float gg = g1[f], bb2 = be1[f], wv = fw[f];
#pragma unroll
        for (int mt = 0; mt < 2; mt++)
#pragma unroll
            for (int r = 0; r < 4; r++)
                fcp[mt][r] += ((v1[mt][i][r] - mu1[mt][r]) * rs1[mt][r] * gg + bb2) * wv;
    }
#pragma unroll
    for (int off = 1; off <= 8; off <<= 1)
#pragma unroll
        for (int mt = 0; mt < 2; mt++)
#pragma unroll
            for (int r = 0; r < 4; r++) fcp[mt][r] += __shfl_xor(fcp[mt][r], off);
    __syncthreads();   // mu1/rs1 reads of reds complete
    if (lm == 0) {
#pragma unroll
        for (int mt = 0; mt < 2; mt++)
#pragma unroll
            for (int r = 0; r < 4; r++)
                reds[w * 32 + mt * 16 + q * 4 + r] = fcp[mt][r];
    }
    __syncthreads();
    if (tid < 32) {
        float tot = fbp[0];
#pragma unroll
        for (int ww = 0; ww < 8; ww++) tot += reds[ww * 32 + tid];
        const int row = r0 + tid;
        const float p = tot * imask[row];
        pred[row] = p;
        if (durpred) durpred[row] = fminf(fmaxf(expf(p) - 1.f, 0.f), MAXDUR_);
    }
}

// ---------------------------------------------------------------------------
// Launch 2: predictors (dur blocks 0..127, pitch 128..255) ∥ mel gather-GEMM
// (blocks 256..511), 512 threads each. __launch_bounds__(512,4): 128-VGPR
// cap -> 2 blocks/CU (16 waves). Predictors first (long blocks start early).
// ---------------------------------------------------------------------------
__global__ __launch_bounds__(512, 4) void mega_kernel(
    const float* __restrict__ enc_out, const float* __restrict__ enc_mask,
    const unsigned short* __restrict__ p0d, const unsigned short* __restrict__ p0p,
    const float* __restrict__ c0b_d, const float* __restrict__ c0b_p,
    const float* __restrict__ g0_d, const float* __restrict__ be0_d,
    const float* __restrict__ g0_p, const float* __restrict__ be0_p,
    const unsigned short* __restrict__ p1d, const unsigned short* __restrict__ p1p,
    const float* __restrict__ c1b_d, const float* __restrict__ c1b_p,
    const float* __restrict__ g1_d, const float* __restrict__ be1_d,
    const float* __restrict__ g1_p, const float* __restrict__ be1_p,
    const float* __restrict__ fw_d, const float* __restrict__ fw_p,
    const float* __restrict__ fb_d, const float* __restrict__ fb_p,
    float* __restrict__ log_dur, float* __restrict__ pitch_prd,
    float* __restrict__ durpred,
    const unsigned short* __restrict__ encb, const int* __restrict__ idx,
    const float* __restrict__ dmask, const unsigned short* __restrict__ pwb,
    const float* __restrict__ pb, float* __restrict__ mel)
{
    __shared__ __align__(16) char smem[SMEM_A];
    const int bxx = blockIdx.x;
    if (bxx < 256) {
        const int z = bxx >> 7;
        predictor_body(bxx & 127, smem,
            enc_out, enc_mask,
            z ? p0p : p0d, z ? c0b_p : c0b_d,
            z ? g0_p : g0_d, z ? be0_p : be0_d,
            z ? p1p : p1d, z ? c1b_p : c1b_d,
            z ? g1_p : g1_d, z ? be1_p : be1_d,
            z ? fw_p : fw_d, z ? fb_p : fb_d,
            z ? pitch_prd : log_dur, z ? nullptr : durpred);
        return;
    }
    // ---- mel branch: 128 j-rows per block, 8 waves x 16 rows each.
    int* ids = (int*)smem;
    const int i  = bxx - 256;
    const int b  = i >> 4;
    const int j0 = (i & 15) * 128;
    const int tid = threadIdx.x;
    if (tid < 128) ids[tid] = idx[b * M_ + j0 + tid];
    __syncthreads();

    const int w = tid >> 6, l = tid & 63;
    const int q = l >> 4, lm = l & 15;
    const int row = ids[w * 16 + lm];
    const unsigned short* ap = encb + ((size_t)(b * 256 + row)) * D_ + q * 8;

    // batch-load all 12 A-chunks upfront (independent, 48 VGPR)
    bf16x8 areg[D_ / 32];
#pragma unroll
    for (int c = 0; c < D_ / 32; c++)
        areg[c] = *(const bf16x8*)(ap + c * 32);

    f32x4_ acc[5];
#pragma unroll
    for (int nt = 0; nt < 5; nt++)
#pragma unroll
        for (int k = 0; k < 4; k++) acc[nt][k] = 0.f;

    // B-stream ping-pong (distance 1)
    bf16x8 bvA[5], bvB[5];
#pragma unroll
    for (int nt = 0; nt < 5; nt++)
        bvA[nt] = *(const bf16x8*)(pwb + (((size_t)0 * 5 + nt) << 9) + l * 8);
    for (int cc = 0; cc < D_ / 32; cc += 2) {
#pragma unroll
        for (int nt = 0; nt < 5; nt++)
            bvB[nt] = *(const bf16x8*)(pwb + (((size_t)(cc + 1) * 5 + nt) << 9) + l * 8);
        __builtin_amdgcn_sched_barrier(0);
#pragma unroll
        for (int nt = 0; nt < 5; nt++)
            acc[nt] = MFMA16(areg[cc], bvA[nt], acc[nt]);
        if (cc + 2 < D_ / 32) {
#pragma unroll
            for (int nt = 0; nt < 5; nt++)
                bvA[nt] = *(const bf16x8*)(pwb + (((size_t)(cc + 2) * 5 + nt) << 9) + l * 8);
        }
        __builtin_amdgcn_sched_barrier(0);
#pragma unroll
        for (int nt = 0; nt < 5; nt++)
            acc[nt] = MFMA16(areg[cc + 1], bvB[nt], acc[nt]);
    }

    float msk[4];
#pragma unroll
    for (int r = 0; r < 4; r++)
        msk[r] = dmask[b * M_ + j0 + w * 16 + q * 4 + r];
#pragma unroll
    for (int nt = 0; nt < 5; nt++) {
        const int n = nt * 16 + lm;
        const float bb = pb[n];
#pragma unroll
        for (int r = 0; r < 4; r++) {
            const int j = j0 + w * 16 + q * 4 + r;
            mel[((size_t)b * M_ + j) * NMEL_ + n] = msk[r] * acc[nt][r] + bb;
        }
    }
}

// ---------------------------------------------------------------------------
extern "C" void kernel_launch(void* const* d_in, const int* in_sizes, int n_in,
                              void* d_out, int out_size, void* d_ws, size_t ws_size,
                              hipStream_t stream)
{
    const float* enc_out   = (const float*)d_in[0];
    const float* enc_mask  = (const float*)d_in[1];
    const float* pitch_tgt = (const float*)d_in[2];
    const int*   durations = (const int*)d_in[3];

    const float* dur_c0_w = (const float*)d_in[4];
    const float* dur_c0_b = (const float*)d_in[5];
    const float* dur_n0_g = (const float*)d_in[6];
    const float* dur_n0_b = (const float*)d_in[7];
    const float* dur_c1_w = (const float*)d_in[8];
    const float* dur_c1_b = (const float*)d_in[9];
    const float* dur_n1_g = (const float*)d_in[10];
    const float* dur_n1_b = (const float*)d_in[11];
    const float* dur_fc_w = (const float*)d_in[12];
    const float* dur_fc_b = (const float*)d_in[13];

    const float* pit_c0_w = (const float*)d_in[14];
    const float* pit_c0_b = (const float*)d_in[15];
    const float* pit_n0_g = (const float*)d_in[16];
    const float* pit_n0_b = (const float*)d_in[17];
    const float* pit_c1_w = (const float*)d_in[18];
    const float* pit_c1_b = (const float*)d_in[19];
    const float* pit_n1_g = (const float*)d_in[20];
    const float* pit_n1_b = (const float*)d_in[21];
    const float* pit_fc_w = (const float*)d_in[22];
    const float* pit_fc_b = (const float*)d_in[23];

    const float* pemb_w = (const float*)d_in[24];
    const float* pemb_b = (const float*)d_in[25];
    const float* proj_w = (const float*)d_in[26];
    const float* proj_b = (const float*)d_in[27];

    // Output slices (flat, in return order), all fp32.
    float* out       = (float*)d_out;
    float* mel_out   = out;                                   // [B,M,NMEL]
    float* dec_mask  = mel_out + (size_t)B_ * M_ * NMEL_;     // [B,M,1]
    float* dur_pred  = dec_mask + (size_t)B_ * M_;            // [B,T]
    float* log_dur   = dur_pred + (size_t)B_ * T_;            // [B,T]
    float* pitch_prd = log_dur + (size_t)B_ * T_;             // [B,T]

    // Workspace layout (~6 MiB)
    char* wp = (char*)d_ws;
    unsigned short* p0d  = (unsigned short*)wp; wp += (size_t)3 * F_ * D_ * 2;  // conv0 w dur
    unsigned short* p0p  = (unsigned short*)wp; wp += (size_t)3 * F_ * D_ * 2;  // conv0 w pitch
    unsigned short* p1d  = (unsigned short*)wp; wp += (size_t)3 * F_ * F_ * 2;  // conv1 w dur
    unsigned short* p1p  = (unsigned short*)wp; wp += (size_t)3 * F_ * F_ * 2;  // conv1 w pitch
    unsigned short* encb = (unsigned short*)wp; wp += (size_t)R_ * D_ * 2;      // enc+pitch bf16
    unsigned short* pwb  = (unsigned short*)wp; wp += (size_t)5 * 12 * 512 * 2; // proj packed
    int*            idx  = (int*)wp;                                            // [B,M]

    // 1: all independent prep (pitch_add x8-vec, regulate, 3x weight repack)
    prep_kernel<<<PREP_BLOCKS, dim3(256), 0, stream>>>(
        enc_out, pitch_tgt, pemb_w, pemb_b,
        durations, idx, dec_mask,
        proj_w, pwb,
        dur_c0_w, pit_c0_w, p0d, p0p,
        dur_c1_w, pit_c1_w, p1d, p1p,
        encb);

    // 2: full predictors (32-row tiles, 256 blocks) ∥ mel gather-GEMM (256)
    mega_kernel<<<512, dim3(512), 0, stream>>>(
        enc_out, enc_mask,
        p0d, p0p, dur_c0_b, pit_c0_b,
        dur_n0_g, dur_n0_b, pit_n0_g, pit_n0_b,
        p1d, p1p, dur_c1_b, pit_c1_b,
        dur_n1_g, dur_n1_b, pit_n1_g, pit_n1_b,
        dur_fc_w, pit_fc_w, dur_fc_b, pit_fc_b,
        log_dur, pitch_prd, dur_pred,
        encb, idx, dec_mask, pwb, proj_b, mel_out);
}